// Round 11
// baseline (9357.935 us; speedup 1.0000x reference)
//
#include <hip/hip_runtime.h>
#include <hip/hip_bf16.h>
#include <math.h>

#define NBATCH 128
#define NATOM  80
#define SENC   80
#define SDEC   160
#define HGDIM  512
#define HIDDIM 256
#define NHEAD  8
#define ROWS_E (NBATCH*NATOM)   /* 10240 */
#define ROWS_D (NBATCH*SDEC)    /* 20480 */

// ---------------- workspace layout (float offsets) ----------------
#define OFF_REAL 0ull
#define OFF_FLAG 10240ull
#define OFF_H    16384ull
#define OFF_LN   (OFF_H  + 5242880ull)
#define OFF_BIG  (OFF_LN + 5242880ull)
#define OFF_AO   (OFF_BIG+ 20971520ull)
#define OFF_DB   (OFF_AO + 5242880ull)
#define OFF_REP  (OFF_DB + 6553600ull)
#define OFF_MOM  (OFF_REP+ 2621440ull)
#define OFF_KL   (OFF_MOM+ 122880ull)
#define NEED_BYTES 184058112ull

// mask dtype probe, atomic-free. flag=1 -> bool bytes, 0 -> int32.
__global__ void k_maskmode(const unsigned char* __restrict__ m, int* __restrict__ flag){
  __shared__ int sh[256];
  int loc = 0;
  for(int i=threadIdx.x; i<ROWS_E; i+=256)
    if((i&3)!=0 && m[i]) loc = 1;
  sh[threadIdx.x] = loc;
  __syncthreads();
  if(threadIdx.x==0){
    int a=0;
    for(int j=0;j<256;j++) a |= sh[j];
    *flag = a;
  }
}

__global__ void k_real(const unsigned char* __restrict__ m, const int* __restrict__ flag,
                       float* __restrict__ real){
  int i = blockIdx.x*256 + threadIdx.x;
  if(i >= ROWS_E) return;
  int v = (*flag) ? (int)m[i] : ((const int*)m)[i];
  real[i] = v ? 0.f : 1.f;
}

__global__ void k_wsfail(float* __restrict__ out, float code){
  if(threadIdx.x==0) out[0] = code;
}

__global__ void k_embed(const float* __restrict__ atom, const float* __restrict__ W,
                        float* __restrict__ h){
  int idx = blockIdx.x*256 + threadIdx.x;
  if(idx >= ROWS_E*HGDIM) return;
  int row = idx >> 9, c = idx & 511;
  float s = 0.f;
  #pragma unroll
  for(int a=0;a<16;a++) s += atom[row*16+a] * W[a*HGDIM+c];
  h[idx] = s;
}

__global__ __launch_bounds__(256) void k_ln(const float* __restrict__ x,
    const float* __restrict__ g, const float* __restrict__ bta,
    float* __restrict__ y, int D){
  size_t row = blockIdx.x;
  const float* xr = x + row*D;
  float* yr = y + row*D;
  int t = threadIdx.x;
  float s=0.f, s2=0.f;
  for(int c=t;c<D;c+=256){ float v=xr[c]; s+=v; s2+=v*v; }
  #pragma unroll
  for(int o=32;o>0;o>>=1){ s += __shfl_xor(s,o); s2 += __shfl_xor(s2,o); }
  __shared__ float ra[4], rb[4];
  int w = t>>6;
  if((t&63)==0){ ra[w]=s; rb[w]=s2; }
  __syncthreads();
  float ts  = ra[0]+ra[1]+ra[2]+ra[3];
  float ts2 = rb[0]+rb[1]+rb[2]+rb[3];
  float mean = ts / D;
  float var  = fmaxf(ts2 / D - mean*mean, 0.f);
  float inv  = rsqrtf(var + 1e-5f);
  for(int c=t;c<D;c+=256){
    float v = (xr[c]-mean)*inv;
    yr[c] = v*g[c] + bta[c];
  }
}

// rbf attention bias for one encoder block: db[b][h][q][k]
__global__ void k_db(const float* __restrict__ coord, const float* __restrict__ real,
                     const float* __restrict__ rbfw, float* __restrict__ db){
  int idx = blockIdx.x*256 + threadIdx.x;
  if(idx >= NBATCH*SENC*SENC) return;
  int b = idx/(SENC*SENC), r = idx%(SENC*SENC), q = r/SENC, k = r%SENC;
  float out[NHEAD];
  bool masked = (real[b*NATOM+k]==0.f) || (k==q);
  if(masked){
    #pragma unroll
    for(int h=0;h<NHEAD;h++) out[h] = -1e9f;
  } else {
    float dx = coord[(b*NATOM+q)*3+0] - coord[(b*NATOM+k)*3+0];
    float dy = coord[(b*NATOM+q)*3+1] - coord[(b*NATOM+k)*3+1];
    float dz = coord[(b*NATOM+q)*3+2] - coord[(b*NATOM+k)*3+2];
    float d  = sqrtf(dx*dx+dy*dy+dz*dz + 1e-12f);
    #pragma unroll
    for(int h=0;h<NHEAD;h++) out[h]=0.f;
    for(int rr=0;rr<16;rr++){
      float cen = (10.f/15.f)*rr;
      float e = __expf(-2.f*(d-cen)*(d-cen));
      #pragma unroll
      for(int h=0;h<NHEAD;h++) out[h] += e * rbfw[rr*NHEAD+h];
    }
  }
  #pragma unroll
  for(int h=0;h<NHEAD;h++)
    db[(((size_t)b*NHEAD+h)*SENC + q)*SENC + k] = out[h];
}

// ===== encoder attention: one block per (b,h); 320 threads, thread=(q,quarter) =====
__global__ __launch_bounds__(320) void k_attn_enc(
    const float* __restrict__ qkv, const float* __restrict__ db,
    float* __restrict__ o_out)
{
  __shared__ float Ps[80][81];
  __shared__ float KV[80][64];
  int bh = blockIdx.x; int h = bh & 7, b = bh >> 3;
  const float* base = qkv + (size_t)b*SENC*1536;
  const float* dbb  = db + (size_t)bh*6400;
  int tid = threadIdx.x;
  for(int idx=tid; idx<80*64; idx+=320){
    int k = idx>>6, d = idx&63;
    KV[k][d] = base[(size_t)k*1536 + 512 + h*64 + d];
  }
  for(int idx=tid; idx<6400; idx+=320){
    int q2 = idx/80, k = idx - q2*80;
    Ps[q2][k] = dbb[idx];
  }
  __syncthreads();
  int q = tid >> 2, part = tid & 3;
  float qr[64];
  {
    const float* qrow = base + (size_t)q*1536 + h*64;
    #pragma unroll
    for(int d=0;d<64;d+=4){
      float4 v = *(const float4*)&qrow[d];
      qr[d]=v.x; qr[d+1]=v.y; qr[d+2]=v.z; qr[d+3]=v.w;
    }
  }
  int k0 = part*20;
  for(int k=k0;k<k0+20;k++){
    float4 s = {0,0,0,0};
    #pragma unroll
    for(int d=0;d<64;d+=4){
      float4 kv = *(const float4*)&KV[k][d];
      s.x += qr[d]*kv.x; s.y += qr[d+1]*kv.y;
      s.z += qr[d+2]*kv.z; s.w += qr[d+3]*kv.w;
    }
    Ps[q][k] += (s.x+s.y+s.z+s.w)*0.125f;
  }
  __syncthreads();
  for(int idx=tid; idx<80*64; idx+=320){
    int k = idx>>6, d = idx&63;
    KV[k][d] = base[(size_t)k*1536 + 1024 + h*64 + d];
  }
  if(tid < 80){
    int qq = tid;
    float m = -1e30f;
    for(int k=0;k<80;k++) m = fmaxf(m, Ps[qq][k]);
    float l = 0.f;
    for(int k=0;k<80;k++){ float e = __expf(Ps[qq][k]-m); Ps[qq][k]=e; l+=e; }
    float inv = 1.f/l;
    for(int k=0;k<80;k++) Ps[qq][k] *= inv;
  }
  __syncthreads();
  int dp = part*16;
  float o[16];
  #pragma unroll
  for(int j=0;j<16;j++) o[j]=0.f;
  for(int k=0;k<80;k++){
    float p = Ps[q][k];
    #pragma unroll
    for(int j=0;j<16;j+=4){
      float4 v = *(const float4*)&KV[k][dp+j];
      o[j] += p*v.x; o[j+1] += p*v.y; o[j+2] += p*v.z; o[j+3] += p*v.w;
    }
  }
  float* orow = o_out + ((size_t)(b*SENC+q))*HGDIM + h*64 + dp;
  #pragma unroll
  for(int j=0;j<16;j+=4){
    float4 v; v.x=o[j]; v.y=o[j+1]; v.z=o[j+2]; v.w=o[j+3];
    *(float4*)&orow[j] = v;
  }
}

// ===== decoder attention: one block per (b,h); online softmax =====
__global__ __launch_bounds__(192) void k_attn_dec(
    const float* __restrict__ qkv, const float* __restrict__ real,
    float* __restrict__ o_out)
{
  __shared__ float Ks[160][32];
  __shared__ float Vs[160][32];
  __shared__ float mb[160];
  int bh = blockIdx.x; int h = bh & 7, b = bh >> 3;
  const float* base = qkv + (size_t)b*SDEC*768;
  int tid = threadIdx.x;
  for(int idx=tid; idx<160*32; idx+=192){
    int k = idx>>5, d = idx&31;
    Ks[k][d] = base[(size_t)k*768 + 256 + h*32 + d];
    Vs[k][d] = base[(size_t)k*768 + 512 + h*32 + d];
  }
  for(int k=tid;k<160;k+=192){
    int kk = (k<80)?k:k-80;
    mb[k] = (real[b*NATOM+kk]==0.f) ? -1e9f : 0.f;
  }
  __syncthreads();
  int q = tid;
  if(q < 160){
    float qr[32];
    const float* qrow = base + (size_t)q*768 + h*32;
    #pragma unroll
    for(int d=0;d<32;d++) qr[d]=qrow[d];
    float m=-1e30f, l=0.f, o[32];
    #pragma unroll
    for(int d=0;d<32;d++) o[d]=0.f;
    for(int k=0;k<160;k++){
      float4 s0 = {0,0,0,0};
      #pragma unroll
      for(int d=0;d<32;d+=4){
        float4 kv = *(const float4*)&Ks[k][d];
        s0.x += qr[d]*kv.x; s0.y += qr[d+1]*kv.y;
        s0.z += qr[d+2]*kv.z; s0.w += qr[d+3]*kv.w;
      }
      float s = (s0.x+s0.y+s0.z+s0.w)*0.17677669529663689f + mb[k];
      float mn = fmaxf(m, s);
      float c = __expf(m - mn);
      float e = __expf(s - mn);
      l = l*c + e;
      #pragma unroll
      for(int d=0;d<32;d+=4){
        float4 v = *(const float4*)&Vs[k][d];
        o[d]   = o[d]*c   + e*v.x;
        o[d+1] = o[d+1]*c + e*v.y;
        o[d+2] = o[d+2]*c + e*v.z;
        o[d+3] = o[d+3]*c + e*v.w;
      }
      m = mn;
    }
    float inv = 1.f/l;
    float* orow = o_out + ((size_t)(b*SDEC+q))*HIDDIM + h*32;
    #pragma unroll
    for(int d=0;d<32;d++) orow[d] = o[d]*inv;
  }
}

// fp32 tiled GEMM, 128x128 tile, scalarized 8x8 accum in named float4 registers.
#define ROWFMA(accL, accH, av) \
  accL.x += (av)*bLo.x; accL.y += (av)*bLo.y; accL.z += (av)*bLo.z; accL.w += (av)*bLo.w; \
  accH.x += (av)*bHi.x; accH.y += (av)*bHi.y; accH.z += (av)*bHi.z; accH.w += (av)*bHi.w;

#define EPI_HALF(c4, colbase) { \
  int col = (colbase); \
  if(bias){ const float4 b4 = *(const float4*)&bias[col]; \
    c4.x += b4.x; c4.y += b4.y; c4.z += b4.z; c4.w += b4.w; } \
  if(resid){ const float4 r4 = *(const float4*)&resid[(size_t)row*Nw + col]; \
    c4.x += r4.x; c4.y += r4.y; c4.z += r4.z; c4.w += r4.w; } \
  if(act==1){ \
    c4.x = c4.x/(1.f+__expf(-c4.x)); c4.y = c4.y/(1.f+__expf(-c4.y)); \
    c4.z = c4.z/(1.f+__expf(-c4.z)); c4.w = c4.w/(1.f+__expf(-c4.w)); } \
  c4.x *= rs; c4.y *= rs; c4.z *= rs; c4.w *= rs; \
  *(float4*)&C[(size_t)row*Nw + col] = c4; }

#define EPI_ROW(accL, accH, ri) { \
  int row = row0 + ty*4 + (((ri)<4) ? (ri) : (60+(ri))); \
  float rs = rowscale ? rowscale[row] : 1.f; \
  EPI_HALF(accL, col0 + tx*4) \
  EPI_HALF(accH, col0 + 64 + tx*4) }

__global__ __launch_bounds__(256) void k_gemm128(
    const float* __restrict__ A, const float* __restrict__ W, const float* __restrict__ bias,
    const float* __restrict__ resid, const float* __restrict__ rowscale,
    float* __restrict__ C,
    int M, int K, int Nw, int act)
{
  __shared__ float As[16][132];  // [k][m]
  __shared__ float Ws[16][132];  // [k][n]
  int tid = threadIdx.x;
  int tx = tid & 15, ty = tid >> 4;
  int row0 = blockIdx.y*128, col0 = blockIdx.x*128;
  int arow = tid >> 2, akq = (tid & 3)*4;
  int wk = tid >> 4, wc = (tid & 15)*4;
  float4 acc0L={0,0,0,0}, acc0H={0,0,0,0}, acc1L={0,0,0,0}, acc1H={0,0,0,0};
  float4 acc2L={0,0,0,0}, acc2H={0,0,0,0}, acc3L={0,0,0,0}, acc3H={0,0,0,0};
  float4 acc4L={0,0,0,0}, acc4H={0,0,0,0}, acc5L={0,0,0,0}, acc5H={0,0,0,0};
  float4 acc6L={0,0,0,0}, acc6H={0,0,0,0}, acc7L={0,0,0,0}, acc7H={0,0,0,0};
  for(int k0=0;k0<K;k0+=16){
    float4 a0 = *(const float4*)&A[(size_t)(row0+arow)*K + k0 + akq];
    float4 a1 = *(const float4*)&A[(size_t)(row0+arow+64)*K + k0 + akq];
    float4 w0 = *(const float4*)&W[(size_t)(k0+wk)*Nw + col0 + wc];
    float4 w1 = *(const float4*)&W[(size_t)(k0+wk)*Nw + col0 + 64 + wc];
    As[akq  ][arow] = a0.x; As[akq+1][arow] = a0.y;
    As[akq+2][arow] = a0.z; As[akq+3][arow] = a0.w;
    As[akq  ][arow+64] = a1.x; As[akq+1][arow+64] = a1.y;
    As[akq+2][arow+64] = a1.z; As[akq+3][arow+64] = a1.w;
    *(float4*)&Ws[wk][wc] = w0;
    *(float4*)&Ws[wk][64+wc] = w1;
    __syncthreads();
    #pragma unroll
    for(int kk=0;kk<16;kk++){
      float4 aLo = *(const float4*)&As[kk][ty*4];
      float4 aHi = *(const float4*)&As[kk][64+ty*4];
      float4 bLo = *(const float4*)&Ws[kk][tx*4];
      float4 bHi = *(const float4*)&Ws[kk][64+tx*4];
      ROWFMA(acc0L, acc0H, aLo.x)
      ROWFMA(acc1L, acc1H, aLo.y)
      ROWFMA(acc2L, acc2H, aLo.z)
      ROWFMA(acc3L, acc3H, aLo.w)
      ROWFMA(acc4L, acc4H, aHi.x)
      ROWFMA(acc5L, acc5H, aHi.y)
      ROWFMA(acc6L, acc6H, aHi.z)
      ROWFMA(acc7L, acc7H, aHi.w)
    }
    __syncthreads();
  }
  EPI_ROW(acc0L, acc0H, 0)
  EPI_ROW(acc1L, acc1H, 1)
  EPI_ROW(acc2L, acc2H, 2)
  EPI_ROW(acc3L, acc3H, 3)
  EPI_ROW(acc4L, acc4H, 4)
  EPI_ROW(acc5L, acc5H, 5)
  EPI_ROW(acc6L, acc6H, 6)
  EPI_ROW(acc7L, acc7H, 7)
}

// thread-per-output GEMM for tiny N
__global__ void k_gemm_small(const float* __restrict__ A, const float* __restrict__ W,
    const float* __restrict__ bias, float* __restrict__ C,
    int M, int K, int Nw, int act){
  int idx = blockIdx.x*256 + threadIdx.x;
  if(idx >= M*Nw) return;
  int row = idx / Nw, col = idx % Nw;
  float s = bias ? bias[col] : 0.f;
  const float* a = A + (size_t)row*K;
  for(int k=0;k<K;k++) s += a[k]*W[(size_t)k*Nw+col];
  if(act==1) s = s/(1.f+__expf(-s));
  C[idx] = s;
}

__global__ __launch_bounds__(256) void k_kl(const float* __restrict__ mom,
    const float* __restrict__ real, float* __restrict__ part){
  int i = blockIdx.x*256 + threadIdx.x;
  float s = 0.f;
  if(i < ROWS_E){
    const float* m = mom + (size_t)i*12;
    float acc = 0.f;
    #pragma unroll
    for(int d=0;d<6;d++){ float mu=m[d], lv=m[6+d]; acc += 1.f + lv - mu*mu - expf(lv); }
    s = acc * real[i];
  }
  #pragma unroll
  for(int o=32;o>0;o>>=1) s += __shfl_xor(s,o);
  __shared__ float r[4];
  if((threadIdx.x&63)==0) r[threadIdx.x>>6]=s;
  __syncthreads();
  if(threadIdx.x==0) part[blockIdx.x] = r[0]+r[1]+r[2]+r[3];
}

__global__ void k_klfin(const float* __restrict__ part, float* __restrict__ o){
  float s=0.f;
  for(int i=0;i<40;i++) s += part[i];
  *o = -0.5f * (s/(float)ROWS_E) * 1e-6f;
}

__global__ __launch_bounds__(256) void k_build_x(
  const float* __restrict__ coord_t, const float* __restrict__ atomics_t, const float* __restrict__ tin,
  const float* __restrict__ qout_w, const float* __restrict__ qout_b, const float* __restrict__ cond,
  const float* __restrict__ lin_w, const float* __restrict__ atom_emb,
  const float* __restrict__ mom, const float* __restrict__ real, float* __restrict__ x)
{
  int idx = blockIdx.x*256 + threadIdx.x;
  if(idx >= NBATCH*SDEC*HIDDIM) return;
  int c = idx & 255; int rowg = idx >> 8; int s = rowg % SDEC; int b = rowg / SDEC;
  int n = (s<NATOM)? s : s-NATOM;
  int j = c >> 1;
  float div = __expf(-(float)(2*j) * (9.210340371976184f/256.f));
  float ang = (float)n * div;
  float pe = (c & 1) ? __cosf(ang) : __sinf(ang);
  float rl = real[b*NATOM + n];
  float v;
  if(s < NATOM){
    int rown = b*NATOM + n;
    float cl = 0.f;
    #pragma unroll
    for(int a=0;a<3;a++) cl += coord_t[rown*3+a] * lin_w[a*HIDDIM+c];
    int bi=0; float bv = atomics_t[rown*16];
    for(int a=1;a<16;a++){ float vv=atomics_t[rown*16+a]; if(vv>bv){bv=vv; bi=a;} }
    float ae = atom_emb[bi*HIDDIM+c];
    float tb = tin[b];
    float tf;
    if(c < 128){
      float fr = __expf(-(float)c * (5.298317366548036f/128.f));
      tf = __sinf(tb*200.f*fr);
    } else {
      float fr = __expf(-(float)(c-128) * (5.298317366548036f/128.f));
      tf = __cosf(tb*200.f*fr);
    }
    v = (cl + ae + pe + tf)*rl + cond[c];
  } else {
    int rown = b*NATOM + n;
    const float* mp = mom + (size_t)rown*12;
    float s2 = qout_b[c];
    #pragma unroll
    for(int d=0;d<6;d++) s2 += mp[d]*qout_w[d*HIDDIM+c];
    v = (s2 + pe)*rl + cond[HIDDIM+c];
  }
  x[idx] = v;
}

__global__ void k_hout(const float* __restrict__ x, const float* __restrict__ real,
                       float* __restrict__ h_out){
  int idx = blockIdx.x*256 + threadIdx.x;
  if(idx >= ROWS_E*HIDDIM) return;
  int c = idx & 255, row = idx >> 8;
  int n = row % NATOM, b = row / NATOM;
  h_out[idx] = x[((size_t)(b*SDEC+n))*HIDDIM + c] * real[row];
}

// ---------------- launch ----------------
extern "C" void kernel_launch(void* const* d_in, const int* in_sizes, int n_in,
                              void* d_out, int out_size, void* d_ws, size_t ws_size,
                              hipStream_t stream){
  (void)in_sizes; (void)n_in; (void)out_size;
  const float* coord_ori   = (const float*)d_in[0];
  const float* atomics_ori = (const float*)d_in[1];
  const unsigned char* pmask = (const unsigned char*)d_in[2];
  const float* coord_t     = (const float*)d_in[3];
  const float* atomics_t   = (const float*)d_in[4];
  const float* t_in        = (const float*)d_in[5];
  const float* enc_embed_w = (const float*)d_in[6];
  const float* rbf_w       = (const float*)d_in[7];
  const float* e_qkv_w=(const float*)d_in[8];  const float* e_qkv_b=(const float*)d_in[9];
  const float* e_out_w=(const float*)d_in[10]; const float* e_out_b=(const float*)d_in[11];
  const float* e_ff1_w=(const float*)d_in[12]; const float* e_ff1_b=(const float*)d_in[13];
  const float* e_ff2_w=(const float*)d_in[14]; const float* e_ff2_b=(const float*)d_in[15];
  const float* e_ln1_g=(const float*)d_in[16]; const float* e_ln1_b=(const float*)d_in[17];
  const float* e_ln2_g=(const float*)d_in[18]; const float* e_ln2_b=(const float*)d_in[19];
  const float* enc_proj_w=(const float*)d_in[20];
  const float* quant_w=(const float*)d_in[21]; const float* quant_b=(const float*)d_in[22];
  const float* qout_w=(const float*)d_in[23];  const float* qout_b=(const float*)d_in[24];
  const float* cond_embed=(const float*)d_in[25];
  const float* lin_embed_w=(const float*)d_in[26];
  const float* atom_embed=(const float*)d_in[27];
  const float* d_qkv_w=(const float*)d_in[28]; const float* d_qkv_b=(const float*)d_in[29];
  const float* d_ow   =(const float*)d_in[30]; const float* d_ob   =(const float*)d_in[31];
  const float* d_ff1_w=(const float*)d_in[32]; const float* d_ff1_b=(const float*)d_in[33];
  const float* d_ff2_w=(const float*)d_in[34]; const float* d_ff2_b=(const float*)d_in[35];
  const float* d_ln1_g=(const float*)d_in[36]; const float* d_ln1_b=(const float*)d_in[37];
  const float* d_ln2_g=(const float*)d_in[38]; const float* d_ln2_b=(const float*)d_in[39];
  const float* oc_ln_g=(const float*)d_in[40]; const float* oc_ln_b=(const float*)d_in[41];
  const float* oc_w   =(const float*)d_in[42];
  const float* oa1_w  =(const float*)d_in[43]; const float* oa1_b=(const float*)d_in[44];
  const float* oa2_w  =(const float*)d_in[45]; const float* oa2_b=(const float*)d_in[46];

  float* ws   = (float*)d_ws;
  float* real = ws + OFF_REAL;
  int*   flag = (int*)(ws + OFF_FLAG);
  float* h    = ws + OFF_H;
  float* lnb  = ws + OFF_LN;
  float* big  = ws + OFF_BIG;
  float* ao   = ws + OFF_AO;
  float* db   = ws + OFF_DB;
  float* rep  = ws + OFF_REP;
  float* mom  = ws + OFF_MOM;
  float* klp  = ws + OFF_KL;
  float* out  = (float*)d_out;

  if(ws_size < NEED_BYTES){
    k_wsfail<<<1,64,0,stream>>>(out, 1.0e6f + (float)(ws_size>>20));
    return;
  }

  k_maskmode<<<1,256,0,stream>>>(pmask, flag);
  k_real <<<40,   256, 0, stream>>>(pmask, flag, real);
  k_embed<<<20480,256, 0, stream>>>(atomics_ori, enc_embed_w, h);

  // ===== encoder =====
  for(int i=0;i<4;i++){
    k_ln<<<ROWS_E,256,0,stream>>>(h, e_ln1_g+i*HGDIM, e_ln1_b+i*HGDIM, lnb, HGDIM);
    k_gemm128<<<dim3(12,80),256,0,stream>>>(lnb, e_qkv_w+(size_t)i*HGDIM*3*HGDIM,
        e_qkv_b+i*3*HGDIM, nullptr, nullptr, big, ROWS_E, HGDIM, 3*HGDIM, 0);
    k_db<<<3200,256,0,stream>>>(coord_ori, real, rbf_w + i*16*NHEAD, db);
    k_attn_enc<<<NBATCH*NHEAD,320,0,stream>>>(big, db, ao);
    k_gemm128<<<dim3(4,80),256,0,stream>>>(ao, e_out_w+(size_t)i*HGDIM*HGDIM,
        e_out_b+i*HGDIM, h, nullptr, h, ROWS_E, HGDIM, HGDIM, 0);
    k_ln<<<ROWS_E,256,0,stream>>>(h, e_ln2_g+i*HGDIM, e_ln2_b+i*HGDIM, lnb, HGDIM);
    k_gemm128<<<dim3(16,80),256,0,stream>>>(lnb, e_ff1_w+(size_t)i*HGDIM*4*HGDIM,
        e_ff1_b+i*4*HGDIM, nullptr, nullptr, big, ROWS_E, HGDIM, 4*HGDIM, 1);
    k_gemm128<<<dim3(4,80),256,0,stream>>>(big, e_ff2_w+(size_t)i*4*HGDIM*HGDIM,
        e_ff2_b+i*HGDIM, h, nullptr, h, ROWS_E, 4*HGDIM, HGDIM, 0);
  }

  k_gemm128<<<dim3(2,80),256,0,stream>>>(h, enc_proj_w, nullptr, nullptr, real,
      rep, ROWS_E, HGDIM, HIDDIM, 0);
  k_gemm_small<<<480,256,0,stream>>>(rep, quant_w, quant_b, mom, ROWS_E, HIDDIM, 12, 0);
  k_kl   <<<40,256,0,stream>>>(mom, real, klp);
  k_klfin<<<1,1,0,stream>>>(klp, out + 194560);

  k_build_x<<<20480,256,0,stream>>>(coord_t, atomics_t, t_in, qout_w, qout_b,
      cond_embed, lin_embed_w, atom_embed, mom, real, h);

  // ===== decoder =====
  for(int i=0;i<8;i++){
    k_ln<<<ROWS_D,256,0,stream>>>(h, d_ln1_g+i*HIDDIM, d_ln1_b+i*HIDDIM, lnb, HIDDIM);
    k_gemm128<<<dim3(6,160),256,0,stream>>>(lnb, d_qkv_w+(size_t)i*HIDDIM*3*HIDDIM,
        d_qkv_b+i*3*HIDDIM, nullptr, nullptr, big, ROWS_D, HIDDIM, 3*HIDDIM, 0);
    k_attn_dec<<<NBATCH*NHEAD,192,0,stream>>>(big, real, ao);
    k_gemm128<<<dim3(2,160),256,0,stream>>>(ao, d_ow+(size_t)i*HIDDIM*HIDDIM,
        d_ob+i*HIDDIM, h, nullptr, h, ROWS_D, HIDDIM, HIDDIM, 0);
    k_ln<<<ROWS_D,256,0,stream>>>(h, d_ln2_g+i*HIDDIM, d_ln2_b+i*HIDDIM, lnb, HIDDIM);
    k_gemm128<<<dim3(8,160),256,0,stream>>>(lnb, d_ff1_w+(size_t)i*HIDDIM*4*HIDDIM,
        d_ff1_b+i*4*HIDDIM, nullptr, nullptr, big, ROWS_D, HIDDIM, 4*HIDDIM, 1);
    k_gemm128<<<dim3(2,160),256,0,stream>>>(big, d_ff2_w+(size_t)i*4*HIDDIM*HIDDIM,
        d_ff2_b+i*HIDDIM, h, nullptr, h, ROWS_D, 4*HIDDIM, HIDDIM, 0);
  }

  // ===== heads =====
  k_hout<<<10240,256,0,stream>>>(h, real, rep);
  k_ln<<<ROWS_E,256,0,stream>>>(rep, oc_ln_g, oc_ln_b, lnb, HIDDIM);
  k_gemm_small<<<120,256,0,stream>>>(lnb, oc_w, nullptr, out, ROWS_E, HIDDIM, 3, 0);
  k_gemm128<<<dim3(2,80),256,0,stream>>>(rep, oa1_w, oa1_b, nullptr, nullptr,
      big, ROWS_E, HIDDIM, HIDDIM, 1);
  k_gemm_small<<<640,256,0,stream>>>(big, oa2_w, oa2_b, out + 30720,
      ROWS_E, HIDDIM, 16, 0);
}

// Round 12
// 4067.247 us; speedup vs baseline: 2.3008x; 2.3008x over previous
//
#include <hip/hip_runtime.h>
#include <hip/hip_bf16.h>
#include <math.h>

#define NBATCH 128
#define NATOM  80
#define SENC   80
#define SDEC   160
#define HGDIM  512
#define HIDDIM 256
#define NHEAD  8
#define ROWS_E (NBATCH*NATOM)   /* 10240 */
#define ROWS_D (NBATCH*SDEC)    /* 20480 */

typedef __hip_bfloat16 bf16;
typedef __attribute__((ext_vector_type(8))) short bf16x8;
typedef __attribute__((ext_vector_type(4))) float f32x4;

// ---------------- workspace layout (float units) ----------------
#define OFF_REAL 0ull                         /* 10240 fp32                 */
#define OFF_FLAG 10240ull                     /* flag                       */
#define OFF_H    16384ull                     /* 5242880 fp32 residual      */
#define OFF_QKV  (OFF_H   + 5242880ull)       /* 15728640 fp32 qkv          */
#define OFF_DB   (OFF_QKV + 15728640ull)      /* 6553600 fp32 enc bias      */
#define OFF_LNB  (OFF_DB  + 6553600ull)       /* 2621440 fl = 5.2M bf16     */
#define OFF_AOB  (OFF_LNB + 2621440ull)       /* 2621440 fl = 5.2M bf16     */
#define OFF_MID  (OFF_AOB + 2621440ull)       /* 10485760 fl = 21M bf16     */
#define OFF_REP  (OFF_MID + 10485760ull)      /* 2621440 fp32               */
#define OFF_MOM  (OFF_REP + 2621440ull)       /* 122880 fp32                */
#define OFF_KL   (OFF_MOM + 122880ull)        /* 64                         */
#define NEED_BYTES 184058112ull

static __device__ __forceinline__ unsigned int packbf2(float a, float b){
  union { bf16 h; unsigned short u; } ua, ub;
  ua.h = __float2bfloat16(a); ub.h = __float2bfloat16(b);
  return (unsigned int)ua.u | ((unsigned int)ub.u << 16);
}

// ---------------- misc kernels ----------------
__global__ void k_maskmode(const unsigned char* __restrict__ m, int* __restrict__ flag){
  __shared__ int sh[256];
  int loc = 0;
  for(int i=threadIdx.x; i<ROWS_E; i+=256)
    if((i&3)!=0 && m[i]) loc = 1;
  sh[threadIdx.x] = loc;
  __syncthreads();
  if(threadIdx.x==0){
    int a=0;
    for(int j=0;j<256;j++) a |= sh[j];
    *flag = a;
  }
}

__global__ void k_real(const unsigned char* __restrict__ m, const int* __restrict__ flag,
                       float* __restrict__ real){
  int i = blockIdx.x*256 + threadIdx.x;
  if(i >= ROWS_E) return;
  int v = (*flag) ? (int)m[i] : ((const int*)m)[i];
  real[i] = v ? 0.f : 1.f;
}

__global__ void k_wsfail(float* __restrict__ out, float code){
  if(threadIdx.x==0) out[0] = code;
}

__global__ void k_embed(const float* __restrict__ atom, const float* __restrict__ W,
                        float* __restrict__ h){
  int idx = blockIdx.x*256 + threadIdx.x;
  if(idx >= ROWS_E*HGDIM) return;
  int row = idx >> 9, c = idx & 511;
  float s = 0.f;
  #pragma unroll
  for(int a=0;a<16;a++) s += atom[row*16+a] * W[a*HGDIM+c];
  h[idx] = s;
}

// LN: fp32 in -> bf16 out
__global__ __launch_bounds__(256) void k_ln(const float* __restrict__ x,
    const float* __restrict__ g, const float* __restrict__ bta,
    bf16* __restrict__ y, int D){
  size_t row = blockIdx.x;
  const float* xr = x + row*D;
  bf16* yr = y + row*D;
  int t = threadIdx.x;
  float s=0.f, s2=0.f;
  for(int c=t;c<D;c+=256){ float v=xr[c]; s+=v; s2+=v*v; }
  #pragma unroll
  for(int o=32;o>0;o>>=1){ s += __shfl_xor(s,o); s2 += __shfl_xor(s2,o); }
  __shared__ float ra[4], rb[4];
  int w = t>>6;
  if((t&63)==0){ ra[w]=s; rb[w]=s2; }
  __syncthreads();
  float ts  = ra[0]+ra[1]+ra[2]+ra[3];
  float ts2 = rb[0]+rb[1]+rb[2]+rb[3];
  float mean = ts / D;
  float var  = fmaxf(ts2 / D - mean*mean, 0.f);
  float inv  = rsqrtf(var + 1e-5f);
  for(int c=t;c<D;c+=256){
    float v = (xr[c]-mean)*inv;
    yr[c] = __float2bfloat16(v*g[c] + bta[c]);
  }
}

// rbf attention bias for one encoder block
__global__ void k_db(const float* __restrict__ coord, const float* __restrict__ real,
                     const float* __restrict__ rbfw, float* __restrict__ db){
  int idx = blockIdx.x*256 + threadIdx.x;
  if(idx >= NBATCH*SENC*SENC) return;
  int b = idx/(SENC*SENC), r = idx%(SENC*SENC), q = r/SENC, k = r%SENC;
  float out[NHEAD];
  bool masked = (real[b*NATOM+k]==0.f) || (k==q);
  if(masked){
    #pragma unroll
    for(int h=0;h<NHEAD;h++) out[h] = -1e9f;
  } else {
    float dx = coord[(b*NATOM+q)*3+0] - coord[(b*NATOM+k)*3+0];
    float dy = coord[(b*NATOM+q)*3+1] - coord[(b*NATOM+k)*3+1];
    float dz = coord[(b*NATOM+q)*3+2] - coord[(b*NATOM+k)*3+2];
    float d  = sqrtf(dx*dx+dy*dy+dz*dz + 1e-12f);
    #pragma unroll
    for(int h=0;h<NHEAD;h++) out[h]=0.f;
    for(int rr=0;rr<16;rr++){
      float cen = (10.f/15.f)*rr;
      float e = __expf(-2.f*(d-cen)*(d-cen));
      #pragma unroll
      for(int h=0;h<NHEAD;h++) out[h] += e * rbfw[rr*NHEAD+h];
    }
  }
  #pragma unroll
  for(int h=0;h<NHEAD;h++)
    db[(((size_t)b*NHEAD+h)*SENC + q)*SENC + k] = out[h];
}

// ===== encoder attention: fp32 qkv in, bf16 out =====
__global__ __launch_bounds__(320) void k_attn_enc(
    const float* __restrict__ qkv, const float* __restrict__ db,
    bf16* __restrict__ o_out)
{
  __shared__ float Ps[80][81];
  __shared__ float KV[80][64];
  int bh = blockIdx.x; int h = bh & 7, b = bh >> 3;
  const float* base = qkv + (size_t)b*SENC*1536;
  const float* dbb  = db + (size_t)bh*6400;
  int tid = threadIdx.x;
  for(int idx=tid; idx<80*64; idx+=320){
    int k = idx>>6, d = idx&63;
    KV[k][d] = base[(size_t)k*1536 + 512 + h*64 + d];
  }
  for(int idx=tid; idx<6400; idx+=320){
    int q2 = idx/80, k = idx - q2*80;
    Ps[q2][k] = dbb[idx];
  }
  __syncthreads();
  int q = tid >> 2, part = tid & 3;
  float qr[64];
  {
    const float* qrow = base + (size_t)q*1536 + h*64;
    #pragma unroll
    for(int d=0;d<64;d+=4){
      float4 v = *(const float4*)&qrow[d];
      qr[d]=v.x; qr[d+1]=v.y; qr[d+2]=v.z; qr[d+3]=v.w;
    }
  }
  int k0 = part*20;
  for(int k=k0;k<k0+20;k++){
    float4 s = {0,0,0,0};
    #pragma unroll
    for(int d=0;d<64;d+=4){
      float4 kv = *(const float4*)&KV[k][d];
      s.x += qr[d]*kv.x; s.y += qr[d+1]*kv.y;
      s.z += qr[d+2]*kv.z; s.w += qr[d+3]*kv.w;
    }
    Ps[q][k] += (s.x+s.y+s.z+s.w)*0.125f;
  }
  __syncthreads();
  for(int idx=tid; idx<80*64; idx+=320){
    int k = idx>>6, d = idx&63;
    KV[k][d] = base[(size_t)k*1536 + 1024 + h*64 + d];
  }
  if(tid < 80){
    int qq = tid;
    float m = -1e30f;
    for(int k=0;k<80;k++) m = fmaxf(m, Ps[qq][k]);
    float l = 0.f;
    for(int k=0;k<80;k++){ float e = __expf(Ps[qq][k]-m); Ps[qq][k]=e; l+=e; }
    float inv = 1.f/l;
    for(int k=0;k<80;k++) Ps[qq][k] *= inv;
  }
  __syncthreads();
  int dp = part*16;
  float o[16];
  #pragma unroll
  for(int j=0;j<16;j++) o[j]=0.f;
  for(int k=0;k<80;k++){
    float p = Ps[q][k];
    #pragma unroll
    for(int j=0;j<16;j+=4){
      float4 v = *(const float4*)&KV[k][dp+j];
      o[j] += p*v.x; o[j+1] += p*v.y; o[j+2] += p*v.z; o[j+3] += p*v.w;
    }
  }
  bf16* orow = o_out + ((size_t)(b*SENC+q))*HGDIM + h*64 + dp;
  #pragma unroll
  for(int j=0;j<16;j++) orow[j] = __float2bfloat16(o[j]);
}

// ===== decoder attention: fp32 qkv in, bf16 out =====
__global__ __launch_bounds__(192) void k_attn_dec(
    const float* __restrict__ qkv, const float* __restrict__ real,
    bf16* __restrict__ o_out)
{
  __shared__ float Ks[160][32];
  __shared__ float Vs[160][32];
  __shared__ float mb[160];
  int bh = blockIdx.x; int h = bh & 7, b = bh >> 3;
  const float* base = qkv + (size_t)b*SDEC*768;
  int tid = threadIdx.x;
  for(int idx=tid; idx<160*32; idx+=192){
    int k = idx>>5, d = idx&31;
    Ks[k][d] = base[(size_t)k*768 + 256 + h*32 + d];
    Vs[k][d] = base[(size_t)k*768 + 512 + h*32 + d];
  }
  for(int k=tid;k<160;k+=192){
    int kk = (k<80)?k:k-80;
    mb[k] = (real[b*NATOM+kk]==0.f) ? -1e9f : 0.f;
  }
  __syncthreads();
  int q = tid;
  if(q < 160){
    float qr[32];
    const float* qrow = base + (size_t)q*768 + h*32;
    #pragma unroll
    for(int d=0;d<32;d++) qr[d]=qrow[d];
    float m=-1e30f, l=0.f, o[32];
    #pragma unroll
    for(int d=0;d<32;d++) o[d]=0.f;
    for(int k=0;k<160;k++){
      float4 s0 = {0,0,0,0};
      #pragma unroll
      for(int d=0;d<32;d+=4){
        float4 kv = *(const float4*)&Ks[k][d];
        s0.x += qr[d]*kv.x; s0.y += qr[d+1]*kv.y;
        s0.z += qr[d+2]*kv.z; s0.w += qr[d+3]*kv.w;
      }
      float s = (s0.x+s0.y+s0.z+s0.w)*0.17677669529663689f + mb[k];
      float mn = fmaxf(m, s);
      float c = __expf(m - mn);
      float e = __expf(s - mn);
      l = l*c + e;
      #pragma unroll
      for(int d=0;d<32;d+=4){
        float4 v = *(const float4*)&Vs[k][d];
        o[d]   = o[d]*c   + e*v.x;
        o[d+1] = o[d+1]*c + e*v.y;
        o[d+2] = o[d+2]*c + e*v.z;
        o[d+3] = o[d+3]*c + e*v.w;
      }
      m = mn;
    }
    float inv = 1.f/l;
    bf16* orow = o_out + ((size_t)(b*SDEC+q))*HIDDIM + h*32;
    #pragma unroll
    for(int d=0;d<32;d++) orow[d] = __float2bfloat16(o[d]*inv);
  }
}

// ===== MFMA bf16 GEMM: C[M,N] = epi(A_bf16[M,K] @ W_f32->bf16[K,N]) =====
// 128x128 tile, BK=32, 4 waves; wave w owns rows w*32..w*32+31.
#define MFM(accv, av, bv) accv = __builtin_amdgcn_mfma_f32_16x16x32_bf16(av, bv, accv, 0, 0, 0);
#define EPIM(accv, rr, cc) { \
  int col = col0 + (cc)*16 + l15; \
  float bi = bias ? bias[col] : 0.f; \
  _Pragma("unroll") \
  for(int j=0;j<4;j++){ \
    int row = row0 + w*32 + (rr)*16 + g*4 + j; \
    float v = accv[j] + bi; \
    if(resid) v += resid[(size_t)row*Nw + col]; \
    if(act==1) v = v/(1.f+__expf(-v)); \
    if(Cf) Cf[(size_t)row*Nw + col] = v; \
    else   Cb[(size_t)row*Nw + col] = __float2bfloat16(v); } }

__global__ __launch_bounds__(256) void k_gemm_mfma(
    const bf16* __restrict__ A, const float* __restrict__ W,
    const float* __restrict__ bias, const float* __restrict__ resid,
    float* __restrict__ Cf, bf16* __restrict__ Cb,
    int M, int K, int Nw, int act)
{
  __shared__ uint4 As4[128][4];   // [row][kchunk] bf16x8 chunks, XOR-swizzled
  __shared__ uint4 Bs4[128][4];   // [col][kchunk]
  int tid = threadIdx.x;
  int w = tid >> 6, lane = tid & 63;
  int l15 = lane & 15, g = lane >> 4;
  int row0 = blockIdx.y*128, col0 = blockIdx.x*128;
  int arow = tid >> 1, ahalf = tid & 1;
  int bn = tid & 127, bkg = tid >> 7;
  int asw = (arow>>1)&3;
  int bsw = (bn>>1)&3;
  int ch = g ^ ((l15>>1)&3);
  f32x4 z = {0.f,0.f,0.f,0.f};
  f32x4 c00=z,c01=z,c02=z,c03=z,c04=z,c05=z,c06=z,c07=z;
  f32x4 c10=z,c11=z,c12=z,c13=z,c14=z,c15=z,c16=z,c17=z;
  for(int k0=0;k0<K;k0+=32){
    const uint4* asrc = (const uint4*)(A + (size_t)(row0+arow)*K + k0);
    uint4 av0 = asrc[ahalf*2];
    uint4 av1 = asrc[ahalf*2+1];
    const float* wsrc = W + (size_t)(k0 + bkg*16)*Nw + col0 + bn;
    uint4 bv0, bv1;
    bv0.x = packbf2(wsrc[0],            wsrc[(size_t)Nw]);
    bv0.y = packbf2(wsrc[(size_t)2*Nw], wsrc[(size_t)3*Nw]);
    bv0.z = packbf2(wsrc[(size_t)4*Nw], wsrc[(size_t)5*Nw]);
    bv0.w = packbf2(wsrc[(size_t)6*Nw], wsrc[(size_t)7*Nw]);
    bv1.x = packbf2(wsrc[(size_t)8*Nw], wsrc[(size_t)9*Nw]);
    bv1.y = packbf2(wsrc[(size_t)10*Nw],wsrc[(size_t)11*Nw]);
    bv1.z = packbf2(wsrc[(size_t)12*Nw],wsrc[(size_t)13*Nw]);
    bv1.w = packbf2(wsrc[(size_t)14*Nw],wsrc[(size_t)15*Nw]);
    As4[arow][(2*ahalf)^asw]   = av0;
    As4[arow][(2*ahalf+1)^asw] = av1;
    Bs4[bn][(2*bkg)^bsw]   = bv0;
    Bs4[bn][(2*bkg+1)^bsw] = bv1;
    __syncthreads();
    bf16x8 a0 = *(const bf16x8*)&As4[w*32 + l15][ch];
    bf16x8 a1 = *(const bf16x8*)&As4[w*32 + 16 + l15][ch];
    bf16x8 b0 = *(const bf16x8*)&Bs4[l15][ch];
    bf16x8 b1 = *(const bf16x8*)&Bs4[16 + l15][ch];
    bf16x8 b2 = *(const bf16x8*)&Bs4[32 + l15][ch];
    bf16x8 b3 = *(const bf16x8*)&Bs4[48 + l15][ch];
    bf16x8 b4 = *(const bf16x8*)&Bs4[64 + l15][ch];
    bf16x8 b5 = *(const bf16x8*)&Bs4[80 + l15][ch];
    bf16x8 b6 = *(const bf16x8*)&Bs4[96 + l15][ch];
    bf16x8 b7 = *(const bf16x8*)&Bs4[112 + l15][ch];
    MFM(c00, a0, b0) MFM(c01, a0, b1) MFM(c02, a0, b2) MFM(c03, a0, b3)
    MFM(c04, a0, b4) MFM(c05, a0, b5) MFM(c06, a0, b6) MFM(c07, a0, b7)
    MFM(c10, a1, b0) MFM(c11, a1, b1) MFM(c12, a1, b2) MFM(c13, a1, b3)
    MFM(c14, a1, b4) MFM(c15, a1, b5) MFM(c16, a1, b6) MFM(c17, a1, b7)
    __syncthreads();
  }
  EPIM(c00, 0, 0) EPIM(c01, 0, 1) EPIM(c02, 0, 2) EPIM(c03, 0, 3)
  EPIM(c04, 0, 4) EPIM(c05, 0, 5) EPIM(c06, 0, 6) EPIM(c07, 0, 7)
  EPIM(c10, 1, 0) EPIM(c11, 1, 1) EPIM(c12, 1, 2) EPIM(c13, 1, 3)
  EPIM(c14, 1, 4) EPIM(c15, 1, 5) EPIM(c16, 1, 6) EPIM(c17, 1, 7)
}

// thread-per-output GEMM for tiny N (A bf16, W fp32)
__global__ void k_gemm_small(const bf16* __restrict__ A, const float* __restrict__ W,
    const float* __restrict__ bias, float* __restrict__ C,
    int M, int K, int Nw, int act){
  int idx = blockIdx.x*256 + threadIdx.x;
  if(idx >= M*Nw) return;
  int row = idx / Nw, col = idx % Nw;
  float s = bias ? bias[col] : 0.f;
  const bf16* a = A + (size_t)row*K;
  for(int k=0;k<K;k++) s += __bfloat162float(a[k])*W[(size_t)k*Nw+col];
  if(act==1) s = s/(1.f+__expf(-s));
  C[idx] = s;
}

__global__ __launch_bounds__(256) void k_kl(const float* __restrict__ mom,
    const float* __restrict__ real, float* __restrict__ part){
  int i = blockIdx.x*256 + threadIdx.x;
  float s = 0.f;
  if(i < ROWS_E){
    const float* m = mom + (size_t)i*12;
    float acc = 0.f;
    #pragma unroll
    for(int d=0;d<6;d++){ float mu=m[d], lv=m[6+d]; acc += 1.f + lv - mu*mu - expf(lv); }
    s = acc * real[i];
  }
  #pragma unroll
  for(int o=32;o>0;o>>=1) s += __shfl_xor(s,o);
  __shared__ float r[4];
  if((threadIdx.x&63)==0) r[threadIdx.x>>6]=s;
  __syncthreads();
  if(threadIdx.x==0) part[blockIdx.x] = r[0]+r[1]+r[2]+r[3];
}

__global__ void k_klfin(const float* __restrict__ part, float* __restrict__ o){
  float s=0.f;
  for(int i=0;i<40;i++) s += part[i];
  *o = -0.5f * (s/(float)ROWS_E) * 1e-6f;
}

// h*real -> bf16 (for proj GEMM input)
__global__ void k_cvtrs(const float* __restrict__ h, const float* __restrict__ real,
                        bf16* __restrict__ o){
  int idx = blockIdx.x*256 + threadIdx.x;
  if(idx >= ROWS_E*HGDIM) return;
  int row = idx >> 9;
  o[idx] = __float2bfloat16(h[idx]*real[row]);
}

__global__ __launch_bounds__(256) void k_build_x(
  const float* __restrict__ coord_t, const float* __restrict__ atomics_t, const float* __restrict__ tin,
  const float* __restrict__ qout_w, const float* __restrict__ qout_b, const float* __restrict__ cond,
  const float* __restrict__ lin_w, const float* __restrict__ atom_emb,
  const float* __restrict__ mom, const float* __restrict__ real, float* __restrict__ x)
{
  int idx = blockIdx.x*256 + threadIdx.x;
  if(idx >= NBATCH*SDEC*HIDDIM) return;
  int c = idx & 255; int rowg = idx >> 8; int s = rowg % SDEC; int b = rowg / SDEC;
  int n = (s<NATOM)? s : s-NATOM;
  int j = c >> 1;
  float div = __expf(-(float)(2*j) * (9.210340371976184f/256.f));
  float ang = (float)n * div;
  float pe = (c & 1) ? __cosf(ang) : __sinf(ang);
  float rl = real[b*NATOM + n];
  float v;
  if(s < NATOM){
    int rown = b*NATOM + n;
    float cl = 0.f;
    #pragma unroll
    for(int a=0;a<3;a++) cl += coord_t[rown*3+a] * lin_w[a*HIDDIM+c];
    int bi=0; float bv = atomics_t[rown*16];
    for(int a=1;a<16;a++){ float vv=atomics_t[rown*16+a]; if(vv>bv){bv=vv; bi=a;} }
    float ae = atom_emb[bi*HIDDIM+c];
    float tb = tin[b];
    float tf;
    if(c < 128){
      float fr = __expf(-(float)c * (5.298317366548036f/128.f));
      tf = __sinf(tb*200.f*fr);
    } else {
      float fr = __expf(-(float)(c-128) * (5.298317366548036f/128.f));
      tf = __cosf(tb*200.f*fr);
    }
    v = (cl + ae + pe + tf)*rl + cond[c];
  } else {
    int rown = b*NATOM + n;
    const float* mp = mom + (size_t)rown*12;
    float s2 = qout_b[c];
    #pragma unroll
    for(int d=0;d<6;d++) s2 += mp[d]*qout_w[d*HIDDIM+c];
    v = (s2 + pe)*rl + cond[HIDDIM+c];
  }
  x[idx] = v;
}

// h_out: fp32 copy (for LN) + bf16 copy (for oa1 GEMM)
__global__ void k_hout(const float* __restrict__ x, const float* __restrict__ real,
                       float* __restrict__ h_out, bf16* __restrict__ h_out_b){
  int idx = blockIdx.x*256 + threadIdx.x;
  if(idx >= ROWS_E*HIDDIM) return;
  int c = idx & 255, row = idx >> 8;
  int n = row % NATOM, b = row / NATOM;
  float v = x[((size_t)(b*SDEC+n))*HIDDIM + c] * real[row];
  h_out[idx] = v;
  h_out_b[idx] = __float2bfloat16(v);
}

// ---------------- launch ----------------
extern "C" void kernel_launch(void* const* d_in, const int* in_sizes, int n_in,
                              void* d_out, int out_size, void* d_ws, size_t ws_size,
                              hipStream_t stream){
  (void)in_sizes; (void)n_in; (void)out_size;
  const float* coord_ori   = (const float*)d_in[0];
  const float* atomics_ori = (const float*)d_in[1];
  const unsigned char* pmask = (const unsigned char*)d_in[2];
  const float* coord_t     = (const float*)d_in[3];
  const float* atomics_t   = (const float*)d_in[4];
  const float* t_in        = (const float*)d_in[5];
  const float* enc_embed_w = (const float*)d_in[6];
  const float* rbf_w       = (const float*)d_in[7];
  const float* e_qkv_w=(const float*)d_in[8];  const float* e_qkv_b=(const float*)d_in[9];
  const float* e_out_w=(const float*)d_in[10]; const float* e_out_b=(const float*)d_in[11];
  const float* e_ff1_w=(const float*)d_in[12]; const float* e_ff1_b=(const float*)d_in[13];
  const float* e_ff2_w=(const float*)d_in[14]; const float* e_ff2_b=(const float*)d_in[15];
  const float* e_ln1_g=(const float*)d_in[16]; const float* e_ln1_b=(const float*)d_in[17];
  const float* e_ln2_g=(const float*)d_in[18]; const float* e_ln2_b=(const float*)d_in[19];
  const float* enc_proj_w=(const float*)d_in[20];
  const float* quant_w=(const float*)d_in[21]; const float* quant_b=(const float*)d_in[22];
  const float* qout_w=(const float*)d_in[23];  const float* qout_b=(const float*)d_in[24];
  const float* cond_embed=(const float*)d_in[25];
  const float* lin_embed_w=(const float*)d_in[26];
  const float* atom_embed=(const float*)d_in[27];
  const float* d_qkv_w=(const float*)d_in[28]; const float* d_qkv_b=(const float*)d_in[29];
  const float* d_ow   =(const float*)d_in[30]; const float* d_ob   =(const float*)d_in[31];
  const float* d_ff1_w=(const float*)d_in[32]; const float* d_ff1_b=(const float*)d_in[33];
  const float* d_ff2_w=(const float*)d_in[34]; const float* d_ff2_b=(const float*)d_in[35];
  const float* d_ln1_g=(const float*)d_in[36]; const float* d_ln1_b=(const float*)d_in[37];
  const float* d_ln2_g=(const float*)d_in[38]; const float* d_ln2_b=(const float*)d_in[39];
  const float* oc_ln_g=(const float*)d_in[40]; const float* oc_ln_b=(const float*)d_in[41];
  const float* oc_w   =(const float*)d_in[42];
  const float* oa1_w  =(const float*)d_in[43]; const float* oa1_b=(const float*)d_in[44];
  const float* oa2_w  =(const float*)d_in[45]; const float* oa2_b=(const float*)d_in[46];

  float* ws   = (float*)d_ws;
  float* real = ws + OFF_REAL;
  int*   flag = (int*)(ws + OFF_FLAG);
  float* h    = ws + OFF_H;
  float* qkv  = ws + OFF_QKV;
  float* db   = ws + OFF_DB;
  bf16*  lnb  = (bf16*)(ws + OFF_LNB);
  bf16*  aob  = (bf16*)(ws + OFF_AOB);
  bf16*  mid  = (bf16*)(ws + OFF_MID);
  float* rep  = ws + OFF_REP;
  float* mom  = ws + OFF_MOM;
  float* klp  = ws + OFF_KL;
  float* out  = (float*)d_out;

  if(ws_size < NEED_BYTES){
    k_wsfail<<<1,64,0,stream>>>(out, 1.0e6f + (float)(ws_size>>20));
    return;
  }

  k_maskmode<<<1,256,0,stream>>>(pmask, flag);
  k_real <<<40,   256, 0, stream>>>(pmask, flag, real);
  k_embed<<<20480,256, 0, stream>>>(atomics_ori, enc_embed_w, h);

  // ===== encoder =====
  for(int i=0;i<4;i++){
    k_ln<<<ROWS_E,256,0,stream>>>(h, e_ln1_g+i*HGDIM, e_ln1_b+i*HGDIM, lnb, HGDIM);
    k_gemm_mfma<<<dim3(12,80),256,0,stream>>>(lnb, e_qkv_w+(size_t)i*HGDIM*3*HGDIM,
        e_qkv_b+i*3*HGDIM, nullptr, qkv, nullptr, ROWS_E, HGDIM, 3*HGDIM, 0);
    k_db<<<3200,256,0,stream>>>(coord_ori, real, rbf_w + i*16*NHEAD, db);
    k_attn_enc<<<NBATCH*NHEAD,320,0,stream>>>(qkv, db, aob);
    k_gemm_mfma<<<dim3(4,80),256,0,stream>>>(aob, e_out_w+(size_t)i*HGDIM*HGDIM,
        e_out_b+i*HGDIM, h, h, nullptr, ROWS_E, HGDIM, HGDIM, 0);
    k_ln<<<ROWS_E,256,0,stream>>>(h, e_ln2_g+i*HGDIM, e_ln2_b+i*HGDIM, lnb, HGDIM);
    k_gemm_mfma<<<dim3(16,80),256,0,stream>>>(lnb, e_ff1_w+(size_t)i*HGDIM*4*HGDIM,
        e_ff1_b+i*4*HGDIM, nullptr, nullptr, mid, ROWS_E, HGDIM, 4*HGDIM, 1);
    k_gemm_mfma<<<dim3(4,80),256,0,stream>>>(mid, e_ff2_w+(size_t)i*4*HGDIM*HGDIM,
        e_ff2_b+i*HGDIM, h, h, nullptr, ROWS_E, 4*HGDIM, HGDIM, 0);
  }

  // rep (bf16 into aob) = (h*real) @ enc_proj
  k_cvtrs<<<20480,256,0,stream>>>(h, real, lnb);
  k_gemm_mfma<<<dim3(2,80),256,0,stream>>>(lnb, enc_proj_w,
      nullptr, nullptr, nullptr, aob, ROWS_E, HGDIM, HIDDIM, 0);
  k_gemm_small<<<480,256,0,stream>>>(aob, quant_w, quant_b, mom, ROWS_E, HIDDIM, 12, 0);
  k_kl   <<<40,256,0,stream>>>(mom, real, klp);
  k_klfin<<<1,1,0,stream>>>(klp, out + 194560);

  k_build_x<<<20480,256,0,stream>>>(coord_t, atomics_t, t_in, qout_w, qout_b,
      cond_embed, lin_embed_w, atom_embed, mom, real, h);

  // ===== decoder =====
  for(int i=0;i<8;i++){
    k_ln<<<ROWS_D,256,0,stream>>>(h, d_ln1_g+i*HIDDIM, d_ln1_b+i*HIDDIM, lnb, HIDDIM);
    k_gemm_mfma<<<dim3(6,160),256,0,stream>>>(lnb, d_qkv_w+(size_t)i*HIDDIM*3*HIDDIM,
        d_qkv_b+i*3*HIDDIM, nullptr, qkv, nullptr, ROWS_D, HIDDIM, 3*HIDDIM, 0);
    k_attn_dec<<<NBATCH*NHEAD,192,0,stream>>>(qkv, real, aob);
    k_gemm_mfma<<<dim3(2,160),256,0,stream>>>(aob, d_ow+(size_t)i*HIDDIM*HIDDIM,
        d_ob+i*HIDDIM, h, h, nullptr, ROWS_D, HIDDIM, HIDDIM, 0);
    k_ln<<<ROWS_D,256,0,stream>>>(h, d_ln2_g+i*HIDDIM, d_ln2_b+i*HIDDIM, lnb, HIDDIM);
    k_gemm_mfma<<<dim3(8,160),256,0,stream>>>(lnb, d_ff1_w+(size_t)i*HIDDIM*4*HIDDIM,
        d_ff1_b+i*4*HIDDIM, nullptr, nullptr, mid, ROWS_D, HIDDIM, 4*HIDDIM, 1);
    k_gemm_mfma<<<dim3(2,160),256,0,stream>>>(mid, d_ff2_w+(size_t)i*4*HIDDIM*HIDDIM,
        d_ff2_b+i*HIDDIM, h, h, nullptr, ROWS_D, 4*HIDDIM, HIDDIM, 0);
  }

  // ===== heads =====
  k_hout<<<10240,256,0,stream>>>(h, real, rep, aob);
  k_ln<<<ROWS_E,256,0,stream>>>(rep, oc_ln_g, oc_ln_b, lnb, HIDDIM);
  k_gemm_small<<<120,256,0,stream>>>(lnb, oc_w, nullptr, out, ROWS_E, HIDDIM, 3, 0);
  k_gemm_mfma<<<dim3(2,80),256,0,stream>>>(aob, oa1_w, oa1_b, nullptr,
      nullptr, mid, ROWS_E, HIDDIM, HIDDIM, 1);
  k_gemm_small<<<640,256,0,stream>>>(mid, oa2_w, oa2_b, out + 30720,
      ROWS_E, HIDDIM, 16, 0);
}